// Round 1
// baseline (1512.032 us; speedup 1.0000x reference)
//
#include <hip/hip_runtime.h>
#include <math.h>

// XLNet two-stream relative attention, f32, correctness-first.
// B=2 S=1024 P=128 HID=1024 NH=16 DH=64

#define NEG_INF_F (-1e9f)

static constexpr int Bc  = 2;
static constexpr int Sc  = 1024;
static constexpr int Pc  = 128;
static constexpr int HIDc = 1024;
static constexpr int NHc = 16;
static constexpr int DHc = 64;

// ---------------------------------------------------------------------------
// segment_matrix dtype sniffing (bool may arrive as u8, i32, or f32)
// mode: 0 = u8/i8, 1 = i32, 2 = f32
__global__ void sniff_seg(const unsigned char* __restrict__ seg, int* __restrict__ flag) {
    const int t = threadIdx.x;   // 64 threads, scan 4096 bytes
    int nz1 = 0, nz23 = 0;
    for (int i = t * 64; i < t * 64 + 64; ++i) {
        unsigned char c = seg[i];
        int m = i & 3;
        if (m == 1 && c) nz1 = 1;
        if ((m == 2 || m == 3) && c) nz23 = 1;
    }
    nz1 = __any(nz1);
    nz23 = __any(nz23);
    if (t == 0) flag[0] = nz1 ? 0 : (nz23 ? 2 : 1);
}

__global__ void norm_seg(const void* __restrict__ seg, const int* __restrict__ flag,
                         unsigned char* __restrict__ out, int n) {
    const int mode = flag[0];
    for (int i = blockIdx.x * blockDim.x + threadIdx.x; i < n; i += gridDim.x * blockDim.x) {
        unsigned char v;
        if (mode == 0)      v = ((const unsigned char*)seg)[i] != 0;
        else if (mode == 1) v = ((const int*)seg)[i] != 0;
        else                v = ((const float*)seg)[i] != 0.0f;
        out[i] = v;
    }
}

// ---------------------------------------------------------------------------
// Simple f32 tiled GEMM: C[M,N] = A[M,K] * B[K,N], all row-major.
// M,N multiples of 64, K multiple of 16. 256 threads, 64x64 tile, 4x4 micro.
__global__ __launch_bounds__(256) void gemm_f32(const float* __restrict__ A,
                                                const float* __restrict__ Bm,
                                                float* __restrict__ C,
                                                int M, int N, int K) {
    __shared__ float As[16][68];
    __shared__ float Bs[16][68];
    const int t  = threadIdx.x;
    const int tr = t >> 4, tc = t & 15;
    const int m0 = blockIdx.y * 64, n0 = blockIdx.x * 64;
    const int ra = t >> 2, ca = (t & 3) * 4;     // A-tile load coords
    const int rb = t >> 4, cbn = (t & 15) * 4;   // B-tile load coords
    float acc[4][4] = {{0.f}};
    for (int k0 = 0; k0 < K; k0 += 16) {
        float4 av = *(const float4*)(A  + (size_t)(m0 + ra) * K + k0 + ca);
        float4 bv = *(const float4*)(Bm + (size_t)(k0 + rb) * N + n0 + cbn);
        __syncthreads();
        As[ca + 0][ra] = av.x; As[ca + 1][ra] = av.y;
        As[ca + 2][ra] = av.z; As[ca + 3][ra] = av.w;
        *(float4*)&Bs[rb][cbn] = bv;
        __syncthreads();
#pragma unroll
        for (int k = 0; k < 16; ++k) {
            float4 a  = *(const float4*)&As[k][tr * 4];
            float4 b4 = *(const float4*)&Bs[k][tc * 4];
            acc[0][0] += a.x * b4.x; acc[0][1] += a.x * b4.y; acc[0][2] += a.x * b4.z; acc[0][3] += a.x * b4.w;
            acc[1][0] += a.y * b4.x; acc[1][1] += a.y * b4.y; acc[1][2] += a.y * b4.z; acc[1][3] += a.y * b4.w;
            acc[2][0] += a.z * b4.x; acc[2][1] += a.z * b4.y; acc[2][2] += a.z * b4.z; acc[2][3] += a.z * b4.w;
            acc[3][0] += a.w * b4.x; acc[3][1] += a.w * b4.y; acc[3][2] += a.w * b4.z; acc[3][3] += a.w * b4.w;
        }
    }
#pragma unroll
    for (int i = 0; i < 4; ++i) {
        float4 r;
        r.x = acc[i][0]; r.y = acc[i][1]; r.z = acc[i][2]; r.w = acc[i][3];
        *(float4*)(C + (size_t)(m0 + tr * 4 + i) * N + n0 + tc * 4) = r;
    }
}

// ---------------------------------------------------------------------------
// qs[b,q,:] = sum_p tm[b,p,q] * qg[b,p,:]   (dense, exact for duplicate targets)
__global__ void scatter_q(const float* __restrict__ tm, const float* __restrict__ qg,
                          float* __restrict__ qs) {
    const int bq = blockIdx.x;
    const int b = bq >> 10, qi = bq & (Sc - 1);
    const int e = threadIdx.x * 4;
    float ax = 0, ay = 0, az = 0, aw = 0;
    const float* tmb = tm + (size_t)b * Pc * Sc + qi;
    const float* qgb = qg + (size_t)b * Pc * HIDc + e;
    for (int p = 0; p < Pc; ++p) {
        float w = tmb[(size_t)p * Sc];
        if (w != 0.0f) {
            float4 v4 = *(const float4*)(qgb + (size_t)p * HIDc);
            ax += w * v4.x; ay += w * v4.y; az += w * v4.z; aw += w * v4.w;
        }
    }
    float4 r; r.x = ax; r.y = ay; r.z = az; r.w = aw;
    *(float4*)(qs + ((size_t)b * Sc + qi) * HIDc + e) = r;
}

// g[b,p,:] = sum_q tm[b,p,q] * attn[b,q,:]
__global__ void gather_o(const float* __restrict__ tm, const float* __restrict__ attn,
                         float* __restrict__ g) {
    const int bp = blockIdx.x;
    const int b = bp >> 7, p = bp & (Pc - 1);
    const int e = threadIdx.x * 4;
    float ax = 0, ay = 0, az = 0, aw = 0;
    const float* tmr = tm + ((size_t)b * Pc + p) * Sc;
    const float* ab  = attn + (size_t)b * Sc * HIDc + e;
    for (int qi = 0; qi < Sc; ++qi) {
        float w = tmr[qi];
        if (w != 0.0f) {
            float4 v4 = *(const float4*)(ab + (size_t)qi * HIDc);
            ax += w * v4.x; ay += w * v4.y; az += w * v4.z; aw += w * v4.w;
        }
    }
    float4 r; r.x = ax; r.y = ay; r.z = az; r.w = aw;
    *(float4*)(g + ((size_t)b * Pc + p) * HIDc + e) = r;
}

// ---------------------------------------------------------------------------
// Fused rel-attention. One block = (b, h, 16 q-rows). 256 threads = 16 rows x 16 lanes.
// score(q,j) = [ (q+cb).kc_j + (q+pb).kp_{S+j-q} + (seg ? d1 : d0) ] / 8 + mask*NEG_INF
// online softmax over j, then PV. Output [B,S,NH,DH].
__global__ __launch_bounds__(256) void attn_f32(
    const float* __restrict__ qsrc, const float* __restrict__ kcp,
    const float* __restrict__ vp,   const float* __restrict__ kpp,
    const float* __restrict__ cb,   const float* __restrict__ pb,
    const float* __restrict__ sb,   const float* __restrict__ senc,
    const unsigned char* __restrict__ segm, const float* __restrict__ maskp,
    float* __restrict__ outp) {
    __shared__ float qc[16][68];
    __shared__ float qp[16][68];
    __shared__ float kcs[64][68];
    __shared__ float vs[64][68];
    __shared__ float kps[80][68];
    __shared__ float ps[16][68];
    __shared__ float d01[16][2];

    const int t  = threadIdx.x;
    const int ty = t >> 4;
    const int tx = t & 15;
    const int q0 = blockIdx.x * 16;
    const int h  = blockIdx.y;
    const int b  = blockIdx.z;
    const int qrow = q0 + ty;

    // load q row fragment + biases, build qc=q+cb, qp=q+pb in LDS; segment dots
    float4 qv  = *(const float4*)(qsrc + (((size_t)b * Sc + qrow) * NHc + h) * DHc + tx * 4);
    float4 cbv = *(const float4*)(cb + h * DHc + tx * 4);
    float4 pbv = *(const float4*)(pb + h * DHc + tx * 4);
    float4 sbv = *(const float4*)(sb + h * DHc + tx * 4);
    float4 e0v = *(const float4*)(senc + (size_t)h * DHc + tx * 4);
    float4 e1v = *(const float4*)(senc + ((size_t)NHc + h) * DHc + tx * 4);

    qc[ty][tx * 4 + 0] = qv.x + cbv.x; qc[ty][tx * 4 + 1] = qv.y + cbv.y;
    qc[ty][tx * 4 + 2] = qv.z + cbv.z; qc[ty][tx * 4 + 3] = qv.w + cbv.w;
    qp[ty][tx * 4 + 0] = qv.x + pbv.x; qp[ty][tx * 4 + 1] = qv.y + pbv.y;
    qp[ty][tx * 4 + 2] = qv.z + pbv.z; qp[ty][tx * 4 + 3] = qv.w + pbv.w;

    float s0 = (qv.x + sbv.x) * e0v.x + (qv.y + sbv.y) * e0v.y +
               (qv.z + sbv.z) * e0v.z + (qv.w + sbv.w) * e0v.w;
    float s1 = (qv.x + sbv.x) * e1v.x + (qv.y + sbv.y) * e1v.y +
               (qv.z + sbv.z) * e1v.z + (qv.w + sbv.w) * e1v.w;
#pragma unroll
    for (int mm = 1; mm < 16; mm <<= 1) {
        s0 += __shfl_xor(s0, mm);
        s1 += __shfl_xor(s1, mm);
    }
    if (tx == 0) { d01[ty][0] = s0; d01[ty][1] = s1; }

    float mrow = -3e38f, lrow = 0.0f;
    float accx = 0, accy = 0, accz = 0, accw = 0;

    const size_t rstride = (size_t)NHc * DHc;
    const float* kcb = kcp + ((size_t)b * Sc * NHc + h) * DHc;
    const float* vb  = vp  + ((size_t)b * Sc * NHc + h) * DHc;
    const float* kpb = kpp + ((size_t)b * 2 * Sc * NHc + h) * DHc;
    const float* maskrow = maskp + ((size_t)b * Sc + qrow) * Sc;
    const unsigned char* segrow = segm + ((size_t)b * Sc + qrow) * Sc;

    for (int j0 = 0; j0 < Sc; j0 += 64) {
        __syncthreads();   // protect LDS tiles from previous-iteration readers
#pragma unroll
        for (int e = 0; e < 4; ++e) {
            int r = ty + e * 16;
            *(float4*)&kcs[r][tx * 4] = *(const float4*)(kcb + (size_t)(j0 + r) * rstride + tx * 4);
            *(float4*)&vs[r][tx * 4]  = *(const float4*)(vb  + (size_t)(j0 + r) * rstride + tx * 4);
        }
        const int base = Sc + j0 - q0 - 15;   // rel index window start; in [1, 2S-79]
#pragma unroll
        for (int e = 0; e < 5; ++e) {
            int r = ty + e * 16;
            if (r < 79)
                *(float4*)&kps[r][tx * 4] = *(const float4*)(kpb + (size_t)(base + r) * rstride + tx * 4);
        }
        __syncthreads();

        float scv[4] = {0.f, 0.f, 0.f, 0.f};
        float spv[4] = {0.f, 0.f, 0.f, 0.f};
#pragma unroll
        for (int d4 = 0; d4 < 16; ++d4) {
            float4 qcv = *(const float4*)&qc[ty][d4 * 4];
            float4 qpv = *(const float4*)&qp[ty][d4 * 4];
#pragma unroll
            for (int jj = 0; jj < 4; ++jj) {
                int jl = jj * 16 + tx;
                float4 kcv = *(const float4*)&kcs[jl][d4 * 4];
                float4 kpv = *(const float4*)&kps[jl - ty + 15][d4 * 4];  // row = S+j-q - base
                scv[jj] += qcv.x * kcv.x + qcv.y * kcv.y + qcv.z * kcv.z + qcv.w * kcv.w;
                spv[jj] += qpv.x * kpv.x + qpv.y * kpv.y + qpv.z * kpv.z + qpv.w * kpv.w;
            }
        }
        float dd0 = d01[ty][0], dd1 = d01[ty][1];
        float smax = -3e38f;
        float sv[4];
#pragma unroll
        for (int jj = 0; jj < 4; ++jj) {
            int j = j0 + jj * 16 + tx;
            float segv = segrow[j] ? dd1 : dd0;
            float s = (scv[jj] + spv[jj] + segv) * 0.125f + maskrow[j] * NEG_INF_F;
            sv[jj] = s;
            smax = fmaxf(smax, s);
        }
#pragma unroll
        for (int mm = 1; mm < 16; mm <<= 1) smax = fmaxf(smax, __shfl_xor(smax, mm));
        float mnew = fmaxf(mrow, smax);
        float corr = __expf(mrow - mnew);
        float lsum = 0.f;
#pragma unroll
        for (int jj = 0; jj < 4; ++jj) {
            float pe = __expf(sv[jj] - mnew);
            ps[ty][jj * 16 + tx] = pe;
            lsum += pe;
        }
#pragma unroll
        for (int mm = 1; mm < 16; mm <<= 1) lsum += __shfl_xor(lsum, mm);
        lrow = lrow * corr + lsum;
        mrow = mnew;
        accx *= corr; accy *= corr; accz *= corr; accw *= corr;
        __syncthreads();   // ps visible to whole row group
#pragma unroll 8
        for (int j2 = 0; j2 < 64; ++j2) {
            float pe = ps[ty][j2];
            float4 vv4 = *(const float4*)&vs[j2][tx * 4];
            accx += pe * vv4.x; accy += pe * vv4.y; accz += pe * vv4.z; accw += pe * vv4.w;
        }
    }
    float inv = 1.0f / lrow;
    float4 res; res.x = accx * inv; res.y = accy * inv; res.z = accz * inv; res.w = accw * inv;
    *(float4*)(outp + (((size_t)b * Sc + qrow) * NHc + h) * DHc + tx * 4) = res;
}

// ---------------------------------------------------------------------------
extern "C" void kernel_launch(void* const* d_in, const int* in_sizes, int n_in,
                              void* d_out, int out_size, void* d_ws, size_t ws_size,
                              hipStream_t stream) {
    const float* content = (const float*)d_in[0];
    const float* querys  = (const float*)d_in[1];
    const float* posenc  = (const float*)d_in[2];
    const void*  segraw  = d_in[3];
    const float* senc    = (const float*)d_in[4];
    const float* sbias   = (const float*)d_in[5];
    const float* cmask   = (const float*)d_in[6];
    const float* qmask   = (const float*)d_in[7];
    const float* tmap    = (const float*)d_in[8];
    const float* cbias   = (const float*)d_in[9];
    const float* pbias   = (const float*)d_in[10];
    const float* wq      = (const float*)d_in[11];
    const float* wkc     = (const float*)d_in[12];
    const float* wv      = (const float*)d_in[13];
    const float* wkp     = (const float*)d_in[14];
    const float* wo      = (const float*)d_in[15];
    float* out = (float*)d_out;

    // workspace layout (bytes), 256-aligned
    char* ws = (char*)d_ws;
    int*  flag   = (int*)ws;                                  //  256 B
    unsigned char* seg_u8 = (unsigned char*)(ws + 256);       //  2 MiB  (B*S*S)
    float* q    = (float*)(ws + 2097408);                     //  8 MiB  [B,S,NH,DH]
    float* kc   = (float*)(ws + 10486016);                    //  8 MiB
    float* v    = (float*)(ws + 18874624);                    //  8 MiB
    float* kp   = (float*)(ws + 27263232);                    // 16 MiB  [B,2S,NH,DH]
    float* qg   = (float*)(ws + 44040448);                    //  1 MiB  [B,P,NH,DH]
    float* attn = (float*)(ws + 45089024);                    //  8 MiB
    float* gath = (float*)(ws + 53477632);                    //  1 MiB  [B,P,HID]

    sniff_seg<<<1, 64, 0, stream>>>((const unsigned char*)segraw, flag);
    norm_seg<<<4096, 256, 0, stream>>>(segraw, flag, seg_u8, Bc * Sc * Sc);

    dim3 blk(256);
    // projections
    gemm_f32<<<dim3(HIDc / 64, (Bc * Sc) / 64), blk, 0, stream>>>(content, wq,  q,  Bc * Sc, HIDc, HIDc);
    gemm_f32<<<dim3(HIDc / 64, (Bc * Sc) / 64), blk, 0, stream>>>(content, wkc, kc, Bc * Sc, HIDc, HIDc);
    gemm_f32<<<dim3(HIDc / 64, (Bc * Sc) / 64), blk, 0, stream>>>(content, wv,  v,  Bc * Sc, HIDc, HIDc);
    gemm_f32<<<dim3(HIDc / 64, (Bc * 2 * Sc) / 64), blk, 0, stream>>>(posenc, wkp, kp, Bc * 2 * Sc, HIDc, HIDc);
    gemm_f32<<<dim3(HIDc / 64, (Bc * Pc) / 64), blk, 0, stream>>>(querys, wq, qg, Bc * Pc, HIDc, HIDc);

    // content stream attention -> output
    attn_f32<<<dim3(Sc / 16, NHc, Bc), blk, 0, stream>>>(q, kc, v, kp, cbias, pbias, sbias,
                                                          senc, seg_u8, cmask, attn);
    gemm_f32<<<dim3(HIDc / 64, (Bc * Sc) / 64), blk, 0, stream>>>(attn, wo, out, Bc * Sc, HIDc, HIDc);

    // query stream: scatter qg into q buffer, attention, gather, project
    scatter_q<<<Bc * Sc, 256, 0, stream>>>(tmap, qg, q);
    attn_f32<<<dim3(Sc / 16, NHc, Bc), blk, 0, stream>>>(q, kc, v, kp, cbias, pbias, sbias,
                                                          senc, seg_u8, qmask, attn);
    gather_o<<<Bc * Pc, 256, 0, stream>>>(tmap, attn, gath);
    gemm_f32<<<dim3(HIDc / 64, (Bc * Pc) / 64), blk, 0, stream>>>(gath, wo, out + (size_t)Bc * Sc * HIDc, Bc * Pc, HIDc, HIDc);
}

// Round 2
// 620.707 us; speedup vs baseline: 2.4360x; 2.4360x over previous
//
#include <hip/hip_runtime.h>
#include <math.h>

// XLNet two-stream relative attention, bf16x3 MFMA everywhere heavy.
// B=2 S=1024 P=128 HID=1024 NH=16 DH=64

#define NEG_INF_F (-1e9f)

static constexpr int Bc  = 2;
static constexpr int Sc  = 1024;
static constexpr int Pc  = 128;
static constexpr int HIDc = 1024;
static constexpr int NHc = 16;
static constexpr int DHc = 64;

typedef __bf16 bf16;
typedef __bf16 bf16x8 __attribute__((ext_vector_type(8)));
typedef float  f32x4  __attribute__((ext_vector_type(4)));

#define MFMA16(a, b, c) __builtin_amdgcn_mfma_f32_16x16x32_bf16((a), (b), (c), 0, 0, 0)

__device__ __forceinline__ void split8(const float* xs, bf16* ph, bf16* pl) {
    union { bf16 v[8]; uint4 u; } H, L;
#pragma unroll
    for (int i = 0; i < 8; ++i) {
        bf16 hb = (bf16)xs[i];
        H.v[i] = hb;
        L.v[i] = (bf16)(xs[i] - (float)hb);
    }
    *(uint4*)ph = H.u;
    *(uint4*)pl = L.u;
}

// ---------------------------------------------------------------------------
// segment_matrix dtype sniffing (bool may arrive as u8, i32, or f32)
__global__ void sniff_seg(const unsigned char* __restrict__ seg, int* __restrict__ flag) {
    const int t = threadIdx.x;
    int nz1 = 0, nz23 = 0;
    for (int i = t * 64; i < t * 64 + 64; ++i) {
        unsigned char c = seg[i];
        int m = i & 3;
        if (m == 1 && c) nz1 = 1;
        if ((m == 2 || m == 3) && c) nz23 = 1;
    }
    nz1 = __any(nz1);
    nz23 = __any(nz23);
    if (t == 0) flag[0] = nz1 ? 0 : (nz23 ? 2 : 1);
}

__global__ void norm_seg(const void* __restrict__ seg, const int* __restrict__ flag,
                         unsigned char* __restrict__ out, int n) {
    const int mode = flag[0];
    for (int i = blockIdx.x * blockDim.x + threadIdx.x; i < n; i += gridDim.x * blockDim.x) {
        unsigned char v;
        if (mode == 0)      v = ((const unsigned char*)seg)[i] != 0;
        else if (mode == 1) v = ((const int*)seg)[i] != 0;
        else                v = ((const float*)seg)[i] != 0.0f;
        out[i] = v;
    }
}

// ---------------------------------------------------------------------------
// W: [K][N] f32 row-major -> Th/Tl: [N][K] bf16 (hi/lo split, transposed)
__global__ __launch_bounds__(256) void transpose_split(const float* __restrict__ W,
                                                       bf16* __restrict__ Th, bf16* __restrict__ Tl,
                                                       int K, int N) {
    __shared__ float tile[32][33];
    const int k0 = blockIdx.y * 32, n0 = blockIdx.x * 32;
    const int c = threadIdx.x & 31, r0 = threadIdx.x >> 5;
#pragma unroll
    for (int rr = 0; rr < 4; ++rr) {
        int r = r0 + rr * 8;
        tile[r][c] = W[(size_t)(k0 + r) * N + n0 + c];
    }
    __syncthreads();
#pragma unroll
    for (int rr = 0; rr < 4; ++rr) {
        int n = r0 + rr * 8;
        float x = tile[c][n];
        bf16 hb = (bf16)x;
        Th[(size_t)(n0 + n) * K + k0 + c] = hb;
        Tl[(size_t)(n0 + n) * K + k0 + c] = (bf16)(x - (float)hb);
    }
}

// ---------------------------------------------------------------------------
// C[M][N] = A[M][K] (f32, split in-kernel) * Bt[N][K]^T (pre-split bf16 hi/lo)
// 128x128 tile, BK=32, 256 threads (4 waves in 2x2), bf16x3.
__global__ __launch_bounds__(256) void gemm_bf16x3(const float* __restrict__ A,
                                                   const bf16* __restrict__ Bth,
                                                   const bf16* __restrict__ Btl,
                                                   float* __restrict__ C,
                                                   int M, int N, int K) {
    __shared__ bf16 Ah[128][40], Al[128][40], Bh[128][40], Bl[128][40];
    const int t = threadIdx.x;
    const int lane = t & 63, wv = t >> 6;
    const int g = lane >> 4, ml = lane & 15;
    const int m0 = blockIdx.y * 128, n0 = blockIdx.x * 128;
    const int moff = (wv & 1) * 64, noff = (wv >> 1) * 64;

    f32x4 acc[4][4];
#pragma unroll
    for (int i = 0; i < 4; ++i)
#pragma unroll
        for (int j = 0; j < 4; ++j) acc[i][j] = (f32x4){0.f, 0.f, 0.f, 0.f};

    const int ar = t >> 3, ac = (t & 7) * 4;
    const int bn = t >> 1, bhh = (t & 1) * 16;

    for (int k0 = 0; k0 < K; k0 += 32) {
        __syncthreads();
#pragma unroll
        for (int rr = 0; rr < 4; ++rr) {
            int row = ar + rr * 32;
            float4 v = *(const float4*)(A + (size_t)(m0 + row) * K + k0 + ac);
            float xs[4] = {v.x, v.y, v.z, v.w};
            union { bf16 b[4]; uint2 u; } H, L;
#pragma unroll
            for (int i = 0; i < 4; ++i) {
                bf16 hb = (bf16)xs[i];
                H.b[i] = hb;
                L.b[i] = (bf16)(xs[i] - (float)hb);
            }
            *(uint2*)&Ah[row][ac] = H.u;
            *(uint2*)&Al[row][ac] = L.u;
        }
        {
            const bf16* srch = Bth + (size_t)(n0 + bn) * K + k0 + bhh;
            const bf16* srcl = Btl + (size_t)(n0 + bn) * K + k0 + bhh;
            *(uint4*)&Bh[bn][bhh]     = *(const uint4*)(srch);
            *(uint4*)&Bh[bn][bhh + 8] = *(const uint4*)(srch + 8);
            *(uint4*)&Bl[bn][bhh]     = *(const uint4*)(srcl);
            *(uint4*)&Bl[bn][bhh + 8] = *(const uint4*)(srcl + 8);
        }
        __syncthreads();
        bf16x8 afh[4], afl[4], bfh[4], bfl[4];
#pragma unroll
        for (int i = 0; i < 4; ++i) {
            afh[i] = *(const bf16x8*)&Ah[moff + i * 16 + ml][g * 8];
            afl[i] = *(const bf16x8*)&Al[moff + i * 16 + ml][g * 8];
            bfh[i] = *(const bf16x8*)&Bh[noff + i * 16 + ml][g * 8];
            bfl[i] = *(const bf16x8*)&Bl[noff + i * 16 + ml][g * 8];
        }
#pragma unroll
        for (int i = 0; i < 4; ++i)
#pragma unroll
            for (int j = 0; j < 4; ++j) {
                acc[i][j] = MFMA16(afl[i], bfh[j], acc[i][j]);
                acc[i][j] = MFMA16(afh[i], bfl[j], acc[i][j]);
                acc[i][j] = MFMA16(afh[i], bfh[j], acc[i][j]);
            }
    }
#pragma unroll
    for (int i = 0; i < 4; ++i)
#pragma unroll
        for (int j = 0; j < 4; ++j)
#pragma unroll
            for (int r = 0; r < 4; ++r)
                C[(size_t)(m0 + moff + i * 16 + g * 4 + r) * N + n0 + noff + j * 16 + ml] = acc[i][j][r];
}

// ---------------------------------------------------------------------------
// qs[b,q,:] = sum_p tm[b,p,q] * qg[b,p,:]
__global__ void scatter_q(const float* __restrict__ tm, const float* __restrict__ qg,
                          float* __restrict__ qs) {
    const int bq = blockIdx.x;
    const int b = bq >> 10, qi = bq & (Sc - 1);
    const int e = threadIdx.x * 4;
    float ax = 0, ay = 0, az = 0, aw = 0;
    const float* tmb = tm + (size_t)b * Pc * Sc + qi;
    const float* qgb = qg + (size_t)b * Pc * HIDc + e;
    for (int p = 0; p < Pc; ++p) {
        float w = tmb[(size_t)p * Sc];
        if (w != 0.0f) {
            float4 v4 = *(const float4*)(qgb + (size_t)p * HIDc);
            ax += w * v4.x; ay += w * v4.y; az += w * v4.z; aw += w * v4.w;
        }
    }
    float4 r; r.x = ax; r.y = ay; r.z = az; r.w = aw;
    *(float4*)(qs + ((size_t)b * Sc + qi) * HIDc + e) = r;
}

// g[b,p,:] = sum_q tm[b,p,q] * attn[b,q,:]
__global__ void gather_o(const float* __restrict__ tm, const float* __restrict__ attn,
                         float* __restrict__ g) {
    const int bp = blockIdx.x;
    const int b = bp >> 7, p = bp & (Pc - 1);
    const int e = threadIdx.x * 4;
    float ax = 0, ay = 0, az = 0, aw = 0;
    const float* tmr = tm + ((size_t)b * Pc + p) * Sc;
    const float* ab  = attn + (size_t)b * Sc * HIDc + e;
    for (int qi = 0; qi < Sc; ++qi) {
        float w = tmr[qi];
        if (w != 0.0f) {
            float4 v4 = *(const float4*)(ab + (size_t)qi * HIDc);
            ax += w * v4.x; ay += w * v4.y; az += w * v4.z; aw += w * v4.w;
        }
    }
    float4 r; r.x = ax; r.y = ay; r.z = az; r.w = aw;
    *(float4*)(g + ((size_t)b * Pc + p) * HIDc + e) = r;
}

// ---------------------------------------------------------------------------
// Fused rel-attention with MFMA. Block: 256 thr = 4 waves, each wave 16 q rows.
// j-step 32. Content + position scores via bf16x3 MFMA; PV via bf16 MFMA.
__global__ __launch_bounds__(256) void attn_mfma(
        const float* __restrict__ qf, int qstride,
        const float* __restrict__ kcf, const float* __restrict__ vf, int kvstride,
        const float* __restrict__ kpf,
        const float* __restrict__ cb, const float* __restrict__ pb,
        const float* __restrict__ sb, const float* __restrict__ senc,
        const unsigned char* __restrict__ segm, const float* __restrict__ maskp,
        float* __restrict__ outp) {
    __shared__ bf16 kc_h[32][72], kc_l[32][72];
    __shared__ bf16 kp_h[96][72], kp_l[96][72];
    __shared__ bf16 vt[64][40];
    __shared__ float Rw[4][16][52];
    __shared__ bf16 Pw[4][16][40];
    __shared__ float d01w[4][16][2];

    const int t = threadIdx.x;
    const int w = t >> 6, lane = t & 63, g = lane >> 4, ml = lane & 15;
    const int q0 = blockIdx.x * 64;
    const int h = blockIdx.y, b = blockIdx.z;

    // ---- hoisted: q fragments (row = ml within wave) + d01 ----
    const int qrow = q0 + w * 16 + ml;
    const float* qrp = qf + (size_t)(b * Sc + qrow) * qstride + h * DHc;
    float qe[16];
    *(float4*)(qe + 0)  = *(const float4*)(qrp + g * 8);
    *(float4*)(qe + 4)  = *(const float4*)(qrp + g * 8 + 4);
    *(float4*)(qe + 8)  = *(const float4*)(qrp + 32 + g * 8);
    *(float4*)(qe + 12) = *(const float4*)(qrp + 32 + g * 8 + 4);
    float cbe[16], pbe[16], sbe[16], e0e[16], e1e[16];
    {
        const float* cbp = cb + h * DHc;
        const float* pbp = pb + h * DHc;
        const float* sbp = sb + h * DHc;
        const float* e0p = senc + h * DHc;
        const float* e1p = senc + NHc * DHc + h * DHc;
#pragma unroll
        for (int kk = 0; kk < 2; ++kk) {
            int o = kk * 32 + g * 8;
            *(float4*)(cbe + kk * 8)     = *(const float4*)(cbp + o);
            *(float4*)(cbe + kk * 8 + 4) = *(const float4*)(cbp + o + 4);
            *(float4*)(pbe + kk * 8)     = *(const float4*)(pbp + o);
            *(float4*)(pbe + kk * 8 + 4) = *(const float4*)(pbp + o + 4);
            *(float4*)(sbe + kk * 8)     = *(const float4*)(sbp + o);
            *(float4*)(sbe + kk * 8 + 4) = *(const float4*)(sbp + o + 4);
            *(float4*)(e0e + kk * 8)     = *(const float4*)(e0p + o);
            *(float4*)(e0e + kk * 8 + 4) = *(const float4*)(e0p + o + 4);
            *(float4*)(e1e + kk * 8)     = *(const float4*)(e1p + o);
            *(float4*)(e1e + kk * 8 + 4) = *(const float4*)(e1p + o + 4);
        }
    }
    bf16x8 qch[2], qcl[2], qph[2], qpl[2];
    float s0 = 0.f, s1 = 0.f;
#pragma unroll
    for (int kk = 0; kk < 2; ++kk) {
#pragma unroll
        for (int i = 0; i < 8; ++i) {
            float qv = qe[kk * 8 + i];
            float xc = qv + cbe[kk * 8 + i];
            float xp = qv + pbe[kk * 8 + i];
            bf16 hb = (bf16)xc;
            qch[kk][i] = hb; qcl[kk][i] = (bf16)(xc - (float)hb);
            hb = (bf16)xp;
            qph[kk][i] = hb; qpl[kk][i] = (bf16)(xp - (float)hb);
            float qs = qv + sbe[kk * 8 + i];
            s0 += qs * e0e[kk * 8 + i];
            s1 += qs * e1e[kk * 8 + i];
        }
    }
    s0 += __shfl_xor(s0, 16); s0 += __shfl_xor(s0, 32);
    s1 += __shfl_xor(s1, 16); s1 += __shfl_xor(s1, 32);
    if (g == 0) { d01w[w][ml][0] = s0; d01w[w][ml][1] = s1; }

    f32x4 oacc[4];
#pragma unroll
    for (int i = 0; i < 4; ++i) oacc[i] = (f32x4){0.f, 0.f, 0.f, 0.f};
    float mrow[4] = {-3e38f, -3e38f, -3e38f, -3e38f};
    float lrow[4] = {0.f, 0.f, 0.f, 0.f};

    const int woff = 48 - w * 16;

    for (int j0 = 0; j0 < Sc; j0 += 32) {
        __syncthreads();
        // ---- staging ----
        {
            int row = t >> 3, c8 = (t & 7) * 8;
            const float* src = kcf + (size_t)(b * Sc + j0 + row) * kvstride + h * DHc + c8;
            float xs[8];
            *(float4*)xs       = *(const float4*)src;
            *(float4*)(xs + 4) = *(const float4*)(src + 4);
            split8(xs, &kc_h[row][c8], &kc_l[row][c8]);
        }
        {
            int jl = t & 31, d0 = (t >> 5) * 8;
            const float* src = vf + (size_t)(b * Sc + j0 + jl) * kvstride + h * DHc + d0;
            float xs[8];
            *(float4*)xs       = *(const float4*)src;
            *(float4*)(xs + 4) = *(const float4*)(src + 4);
#pragma unroll
            for (int i = 0; i < 8; ++i) vt[d0 + i][jl] = (bf16)xs[i];
        }
        {
            const int base = Sc + j0 - q0 - 63;
#pragma unroll
            for (int rr = 0; rr < 3; ++rr) {
                int row = (t >> 3) + rr * 32, c8 = (t & 7) * 8;
                int grow = base + row;
                grow = grow < 0 ? 0 : (grow > 2 * Sc - 1 ? 2 * Sc - 1 : grow);
                const float* src = kpf + ((size_t)b * 2 * Sc + grow) * (NHc * DHc) + h * DHc + c8;
                float xs[8];
                *(float4*)xs       = *(const float4*)src;
                *(float4*)(xs + 4) = *(const float4*)(src + 4);
                split8(xs, &kp_h[row][c8], &kp_l[row][c8]);
            }
        }
        __syncthreads();

        // ---- content scores ----
        f32x4 accc[2];
#pragma unroll
        for (int jt = 0; jt < 2; ++jt) {
            f32x4 a = (f32x4){0.f, 0.f, 0.f, 0.f};
#pragma unroll
            for (int kk = 0; kk < 2; ++kk) {
                bf16x8 bh_ = *(const bf16x8*)&kc_h[jt * 16 + ml][kk * 32 + g * 8];
                bf16x8 bl_ = *(const bf16x8*)&kc_l[jt * 16 + ml][kk * 32 + g * 8];
                a = MFMA16(qcl[kk], bh_, a);
                a = MFMA16(qch[kk], bl_, a);
                a = MFMA16(qch[kk], bh_, a);
            }
            accc[jt] = a;
        }
        // ---- position scores -> Rw ----
#pragma unroll
        for (int ct = 0; ct < 3; ++ct) {
            f32x4 a = (f32x4){0.f, 0.f, 0.f, 0.f};
#pragma unroll
            for (int kk = 0; kk < 2; ++kk) {
                bf16x8 bh_ = *(const bf16x8*)&kp_h[woff + ct * 16 + ml][kk * 32 + g * 8];
                bf16x8 bl_ = *(const bf16x8*)&kp_l[woff + ct * 16 + ml][kk * 32 + g * 8];
                a = MFMA16(qpl[kk], bh_, a);
                a = MFMA16(qph[kk], bl_, a);
                a = MFMA16(qph[kk], bh_, a);
            }
#pragma unroll
            for (int r = 0; r < 4; ++r) Rw[w][g * 4 + r][ct * 16 + ml] = a[r];
        }
        __syncthreads();

        // ---- softmax ----
        float sv[2][4];
#pragma unroll
        for (int jt = 0; jt < 2; ++jt) {
#pragma unroll
            for (int r = 0; r < 4; ++r) {
                int row = g * 4 + r;
                int jc = jt * 16 + ml;
                int qq = q0 + w * 16 + row;
                int j = j0 + jc;
                float pos = Rw[w][row][jc - row + 15];
                unsigned char sg = segm[((size_t)b * Sc + qq) * Sc + j];
                float dsel = sg ? d01w[w][row][1] : d01w[w][row][0];
                float msk = maskp[((size_t)b * Sc + qq) * Sc + j];
                sv[jt][r] = (accc[jt][r] + pos + dsel) * 0.125f + msk * NEG_INF_F;
            }
        }
        float sm[4];
#pragma unroll
        for (int r = 0; r < 4; ++r) sm[r] = fmaxf(sv[0][r], sv[1][r]);
#pragma unroll
        for (int mm = 1; mm < 16; mm <<= 1) {
#pragma unroll
            for (int r = 0; r < 4; ++r) sm[r] = fmaxf(sm[r], __shfl_xor(sm[r], mm));
        }
        float corr[4], psum[4];
#pragma unroll
        for (int r = 0; r < 4; ++r) {
            float mnew = fmaxf(mrow[r], sm[r]);
            corr[r] = __expf(mrow[r] - mnew);
            mrow[r] = mnew;
            psum[r] = 0.f;
        }
#pragma unroll
        for (int jt = 0; jt < 2; ++jt) {
#pragma unroll
            for (int r = 0; r < 4; ++r) {
                float p = __expf(sv[jt][r] - mrow[r]);
                psum[r] += p;
                Pw[w][g * 4 + r][jt * 16 + ml] = (bf16)p;
            }
        }
#pragma unroll
        for (int mm = 1; mm < 16; mm <<= 1) {
#pragma unroll
            for (int r = 0; r < 4; ++r) psum[r] += __shfl_xor(psum[r], mm);
        }
#pragma unroll
        for (int r = 0; r < 4; ++r) {
            lrow[r] = lrow[r] * corr[r] + psum[r];
#pragma unroll
            for (int nt = 0; nt < 4; ++nt) oacc[nt][r] *= corr[r];
        }
        __syncthreads();

        // ---- PV ----
        bf16x8 pa = *(const bf16x8*)&Pw[w][ml][g * 8];
#pragma unroll
        for (int nt = 0; nt < 4; ++nt) {
            bf16x8 vb = *(const bf16x8*)&vt[nt * 16 + ml][g * 8];
            oacc[nt] = MFMA16(pa, vb, oacc[nt]);
        }
    }

    float inv[4];
#pragma unroll
    for (int r = 0; r < 4; ++r) inv[r] = 1.0f / lrow[r];
#pragma unroll
    for (int nt = 0; nt < 4; ++nt)
#pragma unroll
        for (int r = 0; r < 4; ++r)
            outp[((size_t)(b * Sc + q0 + w * 16 + g * 4 + r) * NHc + h) * DHc + nt * 16 + ml] =
                oacc[nt][r] * inv[r];
}

// ---------------------------------------------------------------------------
extern "C" void kernel_launch(void* const* d_in, const int* in_sizes, int n_in,
                              void* d_out, int out_size, void* d_ws, size_t ws_size,
                              hipStream_t stream) {
    const float* content = (const float*)d_in[0];
    const float* querys  = (const float*)d_in[1];
    const float* posenc  = (const float*)d_in[2];
    const void*  segraw  = d_in[3];
    const float* senc    = (const float*)d_in[4];
    const float* sbias   = (const float*)d_in[5];
    const float* cmask   = (const float*)d_in[6];
    const float* qmask   = (const float*)d_in[7];
    const float* tmap    = (const float*)d_in[8];
    const float* cbias   = (const float*)d_in[9];
    const float* pbias   = (const float*)d_in[10];
    const float* wq      = (const float*)d_in[11];
    const float* wkc     = (const float*)d_in[12];
    const float* wv      = (const float*)d_in[13];
    const float* wkp     = (const float*)d_in[14];
    const float* wo      = (const float*)d_in[15];
    float* out = (float*)d_out;

    char* ws = (char*)d_ws;
    size_t off = 0;
    auto take = [&](size_t bytes) -> char* {
        char* p = ws + off;
        off += (bytes + 255) & ~(size_t)255;
        return p;
    };
    int* flag = (int*)take(256);
    unsigned char* seg_u8 = (unsigned char*)take((size_t)Bc * Sc * Sc);
    bf16* wqkvt_h = (bf16*)take((size_t)3 * HIDc * HIDc * 2);
    bf16* wqkvt_l = (bf16*)take((size_t)3 * HIDc * HIDc * 2);
    bf16* wkpt_h  = (bf16*)take((size_t)HIDc * HIDc * 2);
    bf16* wkpt_l  = (bf16*)take((size_t)HIDc * HIDc * 2);
    bf16* wot_h   = (bf16*)take((size_t)HIDc * HIDc * 2);
    bf16* wot_l   = (bf16*)take((size_t)HIDc * HIDc * 2);
    float* qkvf = (float*)take((size_t)Bc * Sc * 3 * HIDc * 4);
    float* kpf  = (float*)take((size_t)Bc * 2 * Sc * HIDc * 4);
    float* attnf = (float*)take((size_t)Bc * Sc * HIDc * 4);
    float* qgf   = (float*)take((size_t)Bc * Pc * HIDc * 4);
    float* qsf   = (float*)take((size_t)Bc * Sc * HIDc * 4);
    float* gathf = (float*)take((size_t)Bc * Pc * HIDc * 4);

    sniff_seg<<<1, 64, 0, stream>>>((const unsigned char*)segraw, flag);
    norm_seg<<<4096, 256, 0, stream>>>(segraw, flag, seg_u8, Bc * Sc * Sc);

    dim3 blk(256);
    dim3 tgrid(HIDc / 32, HIDc / 32);
    transpose_split<<<tgrid, blk, 0, stream>>>(wq,  wqkvt_h,                wqkvt_l,                HIDc, HIDc);
    transpose_split<<<tgrid, blk, 0, stream>>>(wkc, wqkvt_h + HIDc * HIDc,  wqkvt_l + HIDc * HIDc,  HIDc, HIDc);
    transpose_split<<<tgrid, blk, 0, stream>>>(wv,  wqkvt_h + 2 * HIDc * HIDc, wqkvt_l + 2 * HIDc * HIDc, HIDc, HIDc);
    transpose_split<<<tgrid, blk, 0, stream>>>(wkp, wkpt_h, wkpt_l, HIDc, HIDc);
    transpose_split<<<tgrid, blk, 0, stream>>>(wo,  wot_h,  wot_l,  HIDc, HIDc);

    // projections
    gemm_bf16x3<<<dim3(3 * HIDc / 128, (Bc * Sc) / 128), blk, 0, stream>>>(
        content, wqkvt_h, wqkvt_l, qkvf, Bc * Sc, 3 * HIDc, HIDc);
    gemm_bf16x3<<<dim3(HIDc / 128, (Bc * 2 * Sc) / 128), blk, 0, stream>>>(
        posenc, wkpt_h, wkpt_l, kpf, Bc * 2 * Sc, HIDc, HIDc);
    gemm_bf16x3<<<dim3(HIDc / 128, (Bc * Pc) / 128), blk, 0, stream>>>(
        querys, wqkvt_h, wqkvt_l, qgf, Bc * Pc, HIDc, HIDc);

    // content stream
    attn_mfma<<<dim3(Sc / 64, NHc, Bc), blk, 0, stream>>>(
        qkvf, 3 * HIDc, qkvf + HIDc, qkvf + 2 * HIDc, 3 * HIDc, kpf,
        cbias, pbias, sbias, senc, seg_u8, cmask, attnf);
    gemm_bf16x3<<<dim3(HIDc / 128, (Bc * Sc) / 128), blk, 0, stream>>>(
        attnf, wot_h, wot_l, out, Bc * Sc, HIDc, HIDc);

    // query stream
    scatter_q<<<Bc * Sc, 256, 0, stream>>>(tmap, qgf, qsf);
    attn_mfma<<<dim3(Sc / 64, NHc, Bc), blk, 0, stream>>>(
        qsf, HIDc, qkvf + HIDc, qkvf + 2 * HIDc, 3 * HIDc, kpf,
        cbias, pbias, sbias, senc, seg_u8, qmask, attnf);
    gather_o<<<Bc * Pc, 256, 0, stream>>>(tmap, attnf, gathf);
    gemm_bf16x3<<<dim3(HIDc / 128, (Bc * Pc) / 128), blk, 0, stream>>>(
        gathf, wot_h, wot_l, out + (size_t)Bc * Sc * HIDc, Bc * Pc, HIDc, HIDc);
}

// Round 3
// 484.902 us; speedup vs baseline: 3.1182x; 1.2801x over previous
//
#include <hip/hip_runtime.h>
#include <math.h>

// XLNet two-stream relative attention. bf16x3 MFMA GEMMs with pre-split
// planes; fused MFMA attention with bitmask masks + rolling kp window.
// B=2 S=1024 P=128 HID=1024 NH=16 DH=64

#define NEG_INF_F (-1e9f)

static constexpr int Bc  = 2;
static constexpr int Sc  = 1024;
static constexpr int Pc  = 128;
static constexpr int HIDc = 1024;
static constexpr int NHc = 16;
static constexpr int DHc = 64;

typedef __bf16 bf16;
typedef __bf16 bf16x8 __attribute__((ext_vector_type(8)));
typedef float  f32x4  __attribute__((ext_vector_type(4)));

#define MFMA16(a, b, c) __builtin_amdgcn_mfma_f32_16x16x32_bf16((a), (b), (c), 0, 0, 0)

// ---------------------------------------------------------------------------
// segment_matrix dtype sniffing (bool may arrive as u8, i32, or f32)
__global__ void sniff_seg(const unsigned char* __restrict__ seg, int* __restrict__ flag) {
    const int t = threadIdx.x;
    int nz1 = 0, nz23 = 0;
    for (int i = t * 64; i < t * 64 + 64; ++i) {
        unsigned char c = seg[i];
        int m = i & 3;
        if (m == 1 && c) nz1 = 1;
        if ((m == 2 || m == 3) && c) nz23 = 1;
    }
    nz1 = __any(nz1);
    nz23 = __any(nz23);
    if (t == 0) flag[0] = nz1 ? 0 : (nz23 ? 2 : 1);
}

// seg -> bitmask [B*S][32 words]
__global__ void seg_bits_k(const void* __restrict__ seg, const int* __restrict__ flag,
                           unsigned* __restrict__ bits) {
    const int mode = flag[0];
    const int idx = blockIdx.x * 256 + threadIdx.x;     // B*S*32 words
    unsigned wv = 0;
    if (mode == 0) {
        const unsigned char* s = (const unsigned char*)seg + (size_t)idx * 32;
#pragma unroll
        for (int k = 0; k < 32; ++k) wv |= (s[k] != 0) ? (1u << k) : 0u;
    } else if (mode == 1) {
        const int* s = (const int*)seg + (size_t)idx * 32;
#pragma unroll
        for (int k = 0; k < 32; ++k) wv |= (s[k] != 0) ? (1u << k) : 0u;
    } else {
        const float* s = (const float*)seg + (size_t)idx * 32;
#pragma unroll
        for (int k = 0; k < 32; ++k) wv |= (s[k] != 0.f) ? (1u << k) : 0u;
    }
    bits[idx] = wv;
}

// f32 mask [B,1,S,S] -> bitmask
__global__ void mask_bits_k(const float* __restrict__ m, unsigned* __restrict__ bits) {
    const int idx = blockIdx.x * 256 + threadIdx.x;
    const float* s = m + (size_t)idx * 32;
    unsigned wv = 0;
#pragma unroll
    for (int k = 0; k < 32; ++k) wv |= (s[k] != 0.f) ? (1u << k) : 0u;
    bits[idx] = wv;
}

// ---------------------------------------------------------------------------
// W: [K][N] f32 row-major -> Th/Tl: [N][K] bf16 (hi/lo split, transposed)
__global__ __launch_bounds__(256) void transpose_split(const float* __restrict__ W,
                                                       bf16* __restrict__ Th, bf16* __restrict__ Tl,
                                                       int K, int N) {
    __shared__ float tile[32][33];
    const int k0 = blockIdx.y * 32, n0 = blockIdx.x * 32;
    const int c = threadIdx.x & 31, r0 = threadIdx.x >> 5;
#pragma unroll
    for (int rr = 0; rr < 4; ++rr) {
        int r = r0 + rr * 8;
        tile[r][c] = W[(size_t)(k0 + r) * N + n0 + c];
    }
    __syncthreads();
#pragma unroll
    for (int rr = 0; rr < 4; ++rr) {
        int n = r0 + rr * 8;
        float x = tile[c][n];
        bf16 hb = (bf16)x;
        Th[(size_t)(n0 + n) * K + k0 + c] = hb;
        Tl[(size_t)(n0 + n) * K + k0 + c] = (bf16)(x - (float)hb);
    }
}

// f32 array -> hi/lo bf16 planes
__global__ void split_plane(const float* __restrict__ x, bf16* __restrict__ h,
                            bf16* __restrict__ l, int n) {
    int i = (blockIdx.x * 256 + threadIdx.x) * 8;
    if (i >= n) return;
    float xs[8];
    *(float4*)xs       = *(const float4*)(x + i);
    *(float4*)(xs + 4) = *(const float4*)(x + i + 4);
    union { bf16 b[8]; uint4 u; } H, L;
#pragma unroll
    for (int k = 0; k < 8; ++k) {
        bf16 hb = (bf16)xs[k];
        H.b[k] = hb;
        L.b[k] = (bf16)(xs[k] - (float)hb);
    }
    *(uint4*)(h + i) = H.u;
    *(uint4*)(l + i) = L.u;
}

// ---------------------------------------------------------------------------
// bf16x3 GEMM on pre-split planes. C = A * B^T, A planes [M][K], B planes [N][K].
// MODE 0: plain f32 C[M][N].
// MODE 1: qkv fused (N=3072): q->qfo f32, kc->Xh/Xl head-major, v->vfo f32.
// MODE 2: kp: Xh/Xl head-major [B,NH,2S,DH].
template <int MODE>
__global__ __launch_bounds__(256) void gemm3(
        const bf16* __restrict__ Ahp, const bf16* __restrict__ Alp,
        const bf16* __restrict__ Bhp, const bf16* __restrict__ Blp,
        float* __restrict__ Cf,
        bf16* __restrict__ Xh, bf16* __restrict__ Xl,
        float* __restrict__ qfo, float* __restrict__ vfo,
        int M, int N, int K) {
    __shared__ bf16 AhS[128][40], AlS[128][40], BhS[128][40], BlS[128][40];
    const int t = threadIdx.x, lane = t & 63, wv = t >> 6;
    const int g = lane >> 4, ml = lane & 15;
    const int m0 = blockIdx.y * 128, n0 = blockIdx.x * 128;
    const int moff = (wv & 1) * 64, noff = (wv >> 1) * 64;
    const int row2 = t >> 1, c16 = (t & 1) * 16;

    f32x4 acc[4][4];
#pragma unroll
    for (int i = 0; i < 4; ++i)
#pragma unroll
        for (int j = 0; j < 4; ++j) acc[i][j] = (f32x4){0.f, 0.f, 0.f, 0.f};

    for (int k0 = 0; k0 < K; k0 += 32) {
        __syncthreads();
        {
            size_t ab = (size_t)(m0 + row2) * K + k0 + c16;
            *(uint4*)&AhS[row2][c16]     = *(const uint4*)(Ahp + ab);
            *(uint4*)&AhS[row2][c16 + 8] = *(const uint4*)(Ahp + ab + 8);
            *(uint4*)&AlS[row2][c16]     = *(const uint4*)(Alp + ab);
            *(uint4*)&AlS[row2][c16 + 8] = *(const uint4*)(Alp + ab + 8);
            size_t bb = (size_t)(n0 + row2) * K + k0 + c16;
            *(uint4*)&BhS[row2][c16]     = *(const uint4*)(Bhp + bb);
            *(uint4*)&BhS[row2][c16 + 8] = *(const uint4*)(Bhp + bb + 8);
            *(uint4*)&BlS[row2][c16]     = *(const uint4*)(Blp + bb);
            *(uint4*)&BlS[row2][c16 + 8] = *(const uint4*)(Blp + bb + 8);
        }
        __syncthreads();
        bf16x8 afh[4], afl[4], bfh[4], bfl[4];
#pragma unroll
        for (int i = 0; i < 4; ++i) {
            afh[i] = *(const bf16x8*)&AhS[moff + i * 16 + ml][g * 8];
            afl[i] = *(const bf16x8*)&AlS[moff + i * 16 + ml][g * 8];
            bfh[i] = *(const bf16x8*)&BhS[noff + i * 16 + ml][g * 8];
            bfl[i] = *(const bf16x8*)&BlS[noff + i * 16 + ml][g * 8];
        }
#pragma unroll
        for (int i = 0; i < 4; ++i)
#pragma unroll
            for (int j = 0; j < 4; ++j) {
                acc[i][j] = MFMA16(afl[i], bfh[j], acc[i][j]);
                acc[i][j] = MFMA16(afh[i], bfl[j], acc[i][j]);
                acc[i][j] = MFMA16(afh[i], bfh[j], acc[i][j]);
            }
    }
#pragma unroll
    for (int j = 0; j < 4; ++j) {
        const int nb = n0 + noff + j * 16;
#pragma unroll
        for (int i = 0; i < 4; ++i)
#pragma unroll
            for (int r = 0; r < 4; ++r) {
                const int m = m0 + moff + i * 16 + g * 4 + r;
                float val = acc[i][j][r];
                if constexpr (MODE == 0) {
                    Cf[(size_t)m * N + nb + ml] = val;
                } else if constexpr (MODE == 1) {
                    int reg = nb >> 10, nc = nb & 1023;
                    if (reg == 0) {
                        qfo[(size_t)m * 1024 + nc + ml] = val;
                    } else if (reg == 2) {
                        vfo[(size_t)m * 1024 + nc + ml] = val;
                    } else {
                        int hh = nc >> 6, d = (nc & 63) + ml, b = m >> 10, s = m & 1023;
                        size_t o = ((size_t)(b * 16 + hh) * 1024 + s) * 64 + d;
                        bf16 hb = (bf16)val;
                        Xh[o] = hb; Xl[o] = (bf16)(val - (float)hb);
                    }
                } else {
                    int hh = nb >> 6, d = (nb & 63) + ml, b = m >> 11, s = m & 2047;
                    size_t o = ((size_t)(b * 16 + hh) * 2048 + s) * 64 + d;
                    bf16 hb = (bf16)val;
                    Xh[o] = hb; Xl[o] = (bf16)(val - (float)hb);
                }
            }
    }
}

// ---------------------------------------------------------------------------
// vf f32 [B*S][HID] -> vtg bf16 [B,NH,DH,S] (transpose d<->s per head)
__global__ __launch_bounds__(256) void vt_pass(const float* __restrict__ vf,
                                               bf16* __restrict__ vtg) {
    __shared__ float tile[64][65];
    const int s0 = blockIdx.x * 64, h = blockIdx.y, b = blockIdx.z;
    const int t = threadIdx.x;
    const int r = t >> 2, c16 = (t & 3) * 16;
    const float* src = vf + ((size_t)(b * Sc) + s0 + r) * HIDc + h * DHc + c16;
#pragma unroll
    for (int k = 0; k < 4; ++k) {
        float4 v = *(const float4*)(src + k * 4);
        tile[r][c16 + k * 4 + 0] = v.x;
        tile[r][c16 + k * 4 + 1] = v.y;
        tile[r][c16 + k * 4 + 2] = v.z;
        tile[r][c16 + k * 4 + 3] = v.w;
    }
    __syncthreads();
    union { bf16 b[16]; uint4 u[2]; } T;
#pragma unroll
    for (int k = 0; k < 16; ++k) T.b[k] = (bf16)tile[c16 + k][r];
    bf16* dst = vtg + ((size_t)(b * 16 + h) * 64 + r) * 1024 + s0 + c16;
    *(uint4*)(dst)     = T.u[0];
    *(uint4*)(dst + 8) = T.u[1];
}

// ---------------------------------------------------------------------------
// one-hot index extraction from target_mapping rows
__global__ void find_idx(const float* __restrict__ tm, int* __restrict__ idxb,
                         float* __restrict__ wgtb) {
    const int bp = blockIdx.x;   // B*P
    const float* row = tm + (size_t)bp * Sc;
    __shared__ int sidx;
    if (threadIdx.x == 0) sidx = 0;
    __syncthreads();
    for (int j = threadIdx.x; j < Sc; j += 256)
        if (row[j] != 0.f) atomicMax(&sidx, j);
    __syncthreads();
    if (threadIdx.x == 0) { idxb[bp] = sidx; wgtb[bp] = row[sidx]; }
}

// qs[b, idx_p, :] += w * qg[b, p, :]
__global__ void scatter_add(const int* __restrict__ idxb, const float* __restrict__ wgtb,
                            const float* __restrict__ qgf, float* __restrict__ qsf) {
    const int bp = blockIdx.x;
    const int b = bp >> 7;
    const int q = idxb[bp];
    const float w = wgtb[bp];
    const int e = threadIdx.x * 4;
    const float* src = qgf + (size_t)bp * HIDc + e;
    float* dst = qsf + ((size_t)(b * Sc) + q) * HIDc + e;
    float4 v = *(const float4*)src;
    atomicAdd(dst + 0, w * v.x);
    atomicAdd(dst + 1, w * v.y);
    atomicAdd(dst + 2, w * v.z);
    atomicAdd(dst + 3, w * v.w);
}

// g[b,p,:] = w * attn[b, idx_p, :] (reads/writes split planes)
__global__ void gather_o(const int* __restrict__ idxb, const float* __restrict__ wgtb,
                         const bf16* __restrict__ ah, const bf16* __restrict__ al,
                         bf16* __restrict__ gh, bf16* __restrict__ gl) {
    const int bp = blockIdx.x;
    const int b = bp >> 7;
    const int q = idxb[bp];
    const float w = wgtb[bp];
    const int e = threadIdx.x * 4;
    const size_t so = ((size_t)(b * Sc) + q) * HIDc + e;
#pragma unroll
    for (int k = 0; k < 4; ++k) {
        float v = ((float)ah[so + k] + (float)al[so + k]) * w;
        bf16 hb = (bf16)v;
        gh[(size_t)bp * HIDc + e + k] = hb;
        gl[(size_t)bp * HIDc + e + k] = (bf16)(v - (float)hb);
    }
}

// ---------------------------------------------------------------------------
// Fused rel-attention, MFMA, pre-split inputs, bitmask masks, rolling kp.
// Block: 4 waves x 16 q-rows. j-step 32. Output: hi/lo bf16 planes [B*S][HID].
__global__ __launch_bounds__(256) void attn_mfma2(
        const float* __restrict__ qf,
        const bf16* __restrict__ kch, const bf16* __restrict__ kcl,
        const bf16* __restrict__ vtg,
        const bf16* __restrict__ kph, const bf16* __restrict__ kpl,
        const float* __restrict__ cb, const float* __restrict__ pb,
        const float* __restrict__ sb, const float* __restrict__ senc,
        const unsigned* __restrict__ sbits, const unsigned* __restrict__ mbits,
        bf16* __restrict__ aoh, bf16* __restrict__ aol) {
    __shared__ bf16 kc_hS[32][72], kc_lS[32][72];
    __shared__ bf16 kp_hS[128][72], kp_lS[128][72];
    __shared__ bf16 vtS[64][40];
    __shared__ float Rw[4][16][52];
    __shared__ bf16 Pw[4][16][40];
    __shared__ float d01w[4][16][2];

    const int t = threadIdx.x, w = t >> 6, lane = t & 63, g = lane >> 4, ml = lane & 15;
    const int q0 = blockIdx.x * 64, h = blockIdx.y, b = blockIdx.z;

    // ---- q + biases -> fragments, segment dots ----
    const int qrow = q0 + w * 16 + ml;
    const float* qrp = qf + (size_t)(b * Sc + qrow) * HIDc + h * DHc;
    float qe[16], cbe[16], pbe[16], sbe[16], e0e[16], e1e[16];
    {
        const float* cbp = cb + h * DHc;
        const float* pbp = pb + h * DHc;
        const float* sbp = sb + h * DHc;
        const float* e0p = senc + h * DHc;
        const float* e1p = senc + NHc * DHc + h * DHc;
#pragma unroll
        for (int kk = 0; kk < 2; ++kk) {
            int o = kk * 32 + g * 8;
            *(float4*)(qe + kk * 8)      = *(const float4*)(qrp + o);
            *(float4*)(qe + kk * 8 + 4)  = *(const float4*)(qrp + o + 4);
            *(float4*)(cbe + kk * 8)     = *(const float4*)(cbp + o);
            *(float4*)(cbe + kk * 8 + 4) = *(const float4*)(cbp + o + 4);
            *(float4*)(pbe + kk * 8)     = *(const float4*)(pbp + o);
            *(float4*)(pbe + kk * 8 + 4) = *(const float4*)(pbp + o + 4);
            *(float4*)(sbe + kk * 8)     = *(const float4*)(sbp + o);
            *(float4*)(sbe + kk * 8 + 4) = *(const float4*)(sbp + o + 4);
            *(float4*)(e0e + kk * 8)     = *(const float4*)(e0p + o);
            *(float4*)(e0e + kk * 8 + 4) = *(const float4*)(e0p + o + 4);
            *(float4*)(e1e + kk * 8)     = *(const float4*)(e1p + o);
            *(float4*)(e1e + kk * 8 + 4) = *(const float4*)(e1p + o + 4);
        }
    }
    bf16x8 qch[2], qcl[2], qph[2], qpl[2];
    float s0 = 0.f, s1 = 0.f;
#pragma unroll
    for (int kk = 0; kk < 2; ++kk) {
#pragma unroll
        for (int i = 0; i < 8; ++i) {
            float qv = qe[kk * 8 + i];
            float xc = qv + cbe[kk * 8 + i];
            float xp = qv + pbe[kk * 8 + i];
            bf16 hb = (bf16)xc;
            qch[kk][i] = hb; qcl[kk][i] = (bf16)(xc - (float)hb);
            hb = (bf16)xp;
            qph[kk][i] = hb; qpl[kk][i] = (bf16)(xp - (float)hb);
            float qs = qv + sbe[kk * 8 + i];
            s0 += qs * e0e[kk * 8 + i];
            s1 += qs * e1e[kk * 8 + i];
        }
    }
    s0 += __shfl_xor(s0, 16); s0 += __shfl_xor(s0, 32);
    s1 += __shfl_xor(s1, 16); s1 += __shfl_xor(s1, 32);
    if (g == 0) { d01w[w][ml][0] = s0; d01w[w][ml][1] = s1; }
    // intra-wave visible after lgkmcnt
    float d0v[4], d1v[4];
#pragma unroll
    for (int r = 0; r < 4; ++r) {
        d0v[r] = d01w[w][g * 4 + r][0];
        d1v[r] = d01w[w][g * 4 + r][1];
    }

    f32x4 oacc[4];
#pragma unroll
    for (int i = 0; i < 4; ++i) oacc[i] = (f32x4){0.f, 0.f, 0.f, 0.f};
    float mrow[4] = {-3e38f, -3e38f, -3e38f, -3e38f};
    float lrow[4] = {0.f, 0.f, 0.f, 0.f};

    const int woff = 48 - w * 16;
    const int base0 = Sc - q0 - 63;

    const int sprow = t >> 3, spc8 = (t & 7) * 8;       // kp/kc staging coords
    auto stage_kp = [&](int gbase) {
        int grow = gbase + sprow;
        int phys = grow & 127;
        int gcl = grow < 0 ? 0 : (grow > 2 * Sc - 1 ? 2 * Sc - 1 : grow);
        size_t src = ((size_t)(b * 16 + h) * 2048 + gcl) * 64 + spc8;
        *(uint4*)&kp_hS[phys][spc8] = *(const uint4*)(kph + src);
        *(uint4*)&kp_lS[phys][spc8] = *(const uint4*)(kpl + src);
    };
    stage_kp(base0);
    stage_kp(base0 + 32);

    for (int j0 = 0; j0 < Sc; j0 += 32) {
        __syncthreads();
        {   // kc: 32 rows x 64
            size_t src = ((size_t)(b * 16 + h) * 1024 + j0 + sprow) * 64 + spc8;
            *(uint4*)&kc_hS[sprow][spc8] = *(const uint4*)(kch + src);
            *(uint4*)&kc_lS[sprow][spc8] = *(const uint4*)(kcl + src);
        }
        {   // vt: 64 d-rows x 32 j
            int dr = t >> 2, c8 = (t & 3) * 8;
            *(uint4*)&vtS[dr][c8] =
                *(const uint4*)(vtg + ((size_t)(b * 16 + h) * 64 + dr) * 1024 + j0 + c8);
        }
        stage_kp(base0 + j0 + 64);
        __syncthreads();

        // ---- content scores ----
        f32x4 accc[2];
#pragma unroll
        for (int jt = 0; jt < 2; ++jt) {
            f32x4 a = (f32x4){0.f, 0.f, 0.f, 0.f};
#pragma unroll
            for (int kk = 0; kk < 2; ++kk) {
                bf16x8 bh_ = *(const bf16x8*)&kc_hS[jt * 16 + ml][kk * 32 + g * 8];
                bf16x8 bl_ = *(const bf16x8*)&kc_lS[jt * 16 + ml][kk * 32 + g * 8];
                a = MFMA16(qcl[kk], bh_, a);
                a = MFMA16(qch[kk], bl_, a);
                a = MFMA16(qch[kk], bh_, a);
            }
            accc[jt] = a;
        }
        // ---- position scores -> Rw ----
        const int bposw = base0 + j0 + woff;
#pragma unroll
        for (int ct = 0; ct < 3; ++ct) {
            int phys = (bposw + ct * 16 + ml) & 127;
            f32x4 a = (f32x4){0.f, 0.f, 0.f, 0.f};
#pragma unroll
            for (int kk = 0; kk < 2; ++kk) {
                bf16x8 bh_ = *(const bf16x8*)&kp_hS[phys][kk * 32 + g * 8];
                bf16x8 bl_ = *(const bf16x8*)&kp_lS[phys][kk * 32 + g * 8];
                a = MFMA16(qpl[kk], bh_, a);
                a = MFMA16(qph[kk], bl_, a);
                a = MFMA16(qph[kk], bh_, a);
            }
#pragma unroll
            for (int r = 0; r < 4; ++r) Rw[w][g * 4 + r][ct * 16 + ml] = a[r];
        }

        // ---- mask/seg words ----
        unsigned mw[4], sw_[4];
        const int wcol = j0 >> 5;
#pragma unroll
        for (int r = 0; r < 4; ++r) {
            int qq = q0 + w * 16 + g * 4 + r;
            size_t o = (size_t)(b * Sc + qq) * 32 + wcol;
            mw[r]  = mbits[o];
            sw_[r] = sbits[o];
        }

        // ---- softmax ----
        float sv[2][4];
#pragma unroll
        for (int jt = 0; jt < 2; ++jt) {
            int jc = jt * 16 + ml;
#pragma unroll
            for (int r = 0; r < 4; ++r) {
                int row = g * 4 + r;
                float pos = Rw[w][row][jc - row + 15];
                float dsel = ((sw_[r] >> jc) & 1u) ? d1v[r] : d0v[r];
                float s = (accc[jt][r] + pos + dsel) * 0.125f;
                if ((mw[r] >> jc) & 1u) s += NEG_INF_F;
                sv[jt][r] = s;
            }
        }
        float sm[4];
#pragma unroll
        for (int r = 0; r < 4; ++r) sm[r] = fmaxf(sv[0][r], sv[1][r]);
#pragma unroll
        for (int mm = 1; mm < 16; mm <<= 1) {
#pragma unroll
            for (int r = 0; r < 4; ++r) sm[r] = fmaxf(sm[r], __shfl_xor(sm[r], mm));
        }
        float corr[4], psum[4];
#pragma unroll
        for (int r = 0; r < 4; ++r) {
            float mnew = fmaxf(mrow[r], sm[r]);
            corr[r] = __expf(mrow[r] - mnew);
            mrow[r] = mnew;
            psum[r] = 0.f;
        }
#pragma unroll
        for (int jt = 0; jt < 2; ++jt) {
#pragma unroll
            for (int r = 0; r < 4; ++r) {
                float p = __expf(sv[jt][r] - mrow[r]);
                psum[r] += p;
                Pw[w][g * 4 + r][jt * 16 + ml] = (bf16)p;
            }
        }
#pragma unroll
        for (int mm = 1; mm < 16; mm <<= 1) {
#pragma unroll
            for (int r = 0; r < 4; ++r) psum[r] += __shfl_xor(psum[r], mm);
        }
#pragma unroll
        for (int r = 0; r < 4; ++r) {
            lrow[r] = lrow[r] * corr[r] + psum[r];
#pragma unroll
            for (int nt = 0; nt < 4; ++nt) oacc[nt][r] *= corr[r];
        }

        // ---- PV ----
        bf16x8 pa = *(const bf16x8*)&Pw[w][ml][g * 8];
#pragma unroll
        for (int nt = 0; nt < 4; ++nt) {
            bf16x8 vb = *(const bf16x8*)&vtS[nt * 16 + ml][g * 8];
            oacc[nt] = MFMA16(pa, vb, oacc[nt]);
        }
    }

    float inv[4];
#pragma unroll
    for (int r = 0; r < 4; ++r) inv[r] = 1.0f / lrow[r];
#pragma unroll
    for (int nt = 0; nt < 4; ++nt)
#pragma unroll
        for (int r = 0; r < 4; ++r) {
            float val = oacc[nt][r] * inv[r];
            size_t o = (size_t)(b * Sc + q0 + w * 16 + g * 4 + r) * HIDc + h * DHc + nt * 16 + ml;
            bf16 hb = (bf16)val;
            aoh[o] = hb;
            aol[o] = (bf16)(val - (float)hb);
        }
}

// ---------------------------------------------------------------------------
extern "C" void kernel_launch(void* const* d_in, const int* in_sizes, int n_in,
                              void* d_out, int out_size, void* d_ws, size_t ws_size,
                              hipStream_t stream) {
    const float* content = (const float*)d_in[0];
    const float* querys  = (const float*)d_in[1];
    const float* posenc  = (const float*)d_in[2];
    const void*  segraw  = d_in[3];
    const float* senc    = (const float*)d_in[4];
    const float* sbias   = (const float*)d_in[5];
    const float* cmask   = (const float*)d_in[6];
    const float* qmask   = (const float*)d_in[7];
    const float* tmap    = (const float*)d_in[8];
    const float* cbias   = (const float*)d_in[9];
    const float* pbias   = (const float*)d_in[10];
    const float* wq      = (const float*)d_in[11];
    const float* wkc     = (const float*)d_in[12];
    const float* wv      = (const float*)d_in[13];
    const float* wkp     = (const float*)d_in[14];
    const float* wo      = (const float*)d_in[15];
    float* out = (float*)d_out;

    char* ws = (char*)d_ws;
    size_t off = 0;
    auto take = [&](size_t bytes) -> char* {
        char* p = ws + off;
        off += (bytes + 255) & ~(size_t)255;
        return p;
    };
    int*      flag   = (int*)take(256);
    int*      idxb   = (int*)take(Bc * Pc * 4);
    float*    wgtb   = (float*)take(Bc * Pc * 4);
    unsigned* segb   = (unsigned*)take((size_t)Bc * Sc * 32 * 4);
    unsigned* cmb    = (unsigned*)take((size_t)Bc * Sc * 32 * 4);
    unsigned* qmb    = (unsigned*)take((size_t)Bc * Sc * 32 * 4);
    bf16* wqkvh = (bf16*)take((size_t)3 * HIDc * HIDc * 2);
    bf16* wqkvl = (bf16*)take((size_t)3 * HIDc * HIDc * 2);
    bf16* wkph  = (bf16*)take((size_t)HIDc * HIDc * 2);
    bf16* wkpl  = (bf16*)take((size_t)HIDc * HIDc * 2);
    bf16* woh   = (bf16*)take((size_t)HIDc * HIDc * 2);
    bf16* wol   = (bf16*)take((size_t)HIDc * HIDc * 2);
    bf16* conth = (bf16*)take((size_t)Bc * Sc * HIDc * 2);
    bf16* contl = (bf16*)take((size_t)Bc * Sc * HIDc * 2);
    bf16* posh  = (bf16*)take((size_t)Bc * 2 * Sc * HIDc * 2);
    bf16* posl  = (bf16*)take((size_t)Bc * 2 * Sc * HIDc * 2);
    bf16* quh   = (bf16*)take((size_t)Bc * Pc * HIDc * 2);
    bf16* qul   = (bf16*)take((size_t)Bc * Pc * HIDc * 2);
    float* qf   = (float*)take((size_t)Bc * Sc * HIDc * 4);   // also reused as qs
    float* vf   = (float*)take((size_t)Bc * Sc * HIDc * 4);
    bf16* kchp  = (bf16*)take((size_t)Bc * NHc * Sc * DHc * 2);
    bf16* kclp  = (bf16*)take((size_t)Bc * NHc * Sc * DHc * 2);
    bf16* kphp  = (bf16*)take((size_t)Bc * NHc * 2 * Sc * DHc * 2);
    bf16* kplp  = (bf16*)take((size_t)Bc * NHc * 2 * Sc * DHc * 2);
    bf16* vtg   = (bf16*)take((size_t)Bc * NHc * DHc * Sc * 2);
    float* qgf  = (float*)take((size_t)Bc * Pc * HIDc * 4);
    bf16* aoh   = (bf16*)take((size_t)Bc * Sc * HIDc * 2);
    bf16* aol   = (bf16*)take((size_t)Bc * Sc * HIDc * 2);
    bf16* gathh = (bf16*)take((size_t)Bc * Pc * HIDc * 2);
    bf16* gathl = (bf16*)take((size_t)Bc * Pc * HIDc * 2);

    dim3 blk(256);

    // ---- prep ----
    sniff_seg<<<1, 64, 0, stream>>>((const unsigned char*)segraw, flag);
    seg_bits_k<<<(Bc * Sc * 32) / 256, blk, 0, stream>>>(segraw, flag, segb);
    mask_bits_k<<<(Bc * Sc * 32) / 256, blk, 0, stream>>>(cmask, cmb);
    mask_bits_k<<<(Bc * Sc * 32) / 256, blk, 0, stream>>>(qmask, qmb);
    find_idx<<<Bc * Pc, blk, 0, stream>>>(tmap, idxb, wgtb);

    dim3 tgrid(HIDc / 32, HIDc / 32);
    transpose_split<<<tgrid, blk, 0, stream>>>(wq,  wqkvh,                    wqkvl,                    HIDc, HIDc);
    transpose_split<<<tgrid, blk, 0, stream>>>(wkc, wqkvh + HIDc * HIDc,     wqkvl + HIDc * HIDc,      HIDc, HIDc);
    transpose_split<<<tgrid, blk, 0, stream>>>(wv,  wqkvh + 2 * HIDc * HIDc, wqkvl + 2 * HIDc * HIDc,  HIDc, HIDc);
    transpose_split<<<tgrid, blk, 0, stream>>>(wkp, wkph, wkpl, HIDc, HIDc);
    transpose_split<<<tgrid, blk, 0, stream>>>(wo,  woh,  wol,  HIDc, HIDc);

    split_plane<<<(Bc * Sc * HIDc) / 2048, blk, 0, stream>>>(content, conth, contl, Bc * Sc * HIDc);
    split_plane<<<(Bc * 2 * Sc * HIDc) / 2048, blk, 0, stream>>>(posenc, posh, posl, Bc * 2 * Sc * HIDc);
    split_plane<<<(Bc * Pc * HIDc) / 2048, blk, 0, stream>>>(querys, quh, qul, Bc * Pc * HIDc);

    // ---- projections ----
    gemm3<1><<<dim3(3 * HIDc / 128, (Bc * Sc) / 128), blk, 0, stream>>>(
        conth, contl, wqkvh, wqkvl, nullptr, kchp, kclp, qf, vf, Bc * Sc, 3 * HIDc, HIDc);
    gemm3<2><<<dim3(HIDc / 128, (Bc * 2 * Sc) / 128), blk, 0, stream>>>(
        posh, posl, wkph, wkpl, nullptr, kphp, kplp, nullptr, nullptr, Bc * 2 * Sc, HIDc, HIDc);
    gemm3<0><<<dim3(HIDc / 128, (Bc * Pc) / 128), blk, 0, stream>>>(
        quh, qul, wqkvh, wqkvl, qgf, nullptr, nullptr, nullptr, nullptr, Bc * Pc, HIDc, HIDc);
    vt_pass<<<dim3(Sc / 64, NHc, Bc), blk, 0, stream>>>(vf, vtg);

    // ---- content stream ----
    attn_mfma2<<<dim3(Sc / 64, NHc, Bc), blk, 0, stream>>>(
        qf, kchp, kclp, vtg, kphp, kplp, cbias, pbias, sbias, senc, segb, cmb, aoh, aol);
    gemm3<0><<<dim3(HIDc / 128, (Bc * Sc) / 128), blk, 0, stream>>>(
        aoh, aol, woh, wol, out, nullptr, nullptr, nullptr, nullptr, Bc * Sc, HIDc, HIDc);

    // ---- query stream ----
    hipMemsetAsync(qf, 0, (size_t)Bc * Sc * HIDc * 4, stream);
    scatter_add<<<Bc * Pc, blk, 0, stream>>>(idxb, wgtb, qgf, qf);
    attn_mfma2<<<dim3(Sc / 64, NHc, Bc), blk, 0, stream>>>(
        qf, kchp, kclp, vtg, kphp, kplp, cbias, pbias, sbias, senc, segb, qmb, aoh, aol);
    gather_o<<<Bc * Pc, blk, 0, stream>>>(idxb, wgtb, aoh, aol, gathh, gathl);
    gemm3<0><<<dim3(HIDc / 128, (Bc * Pc) / 128), blk, 0, stream>>>(
        gathh, gathl, woh, wol, out + (size_t)Bc * Sc * HIDc, nullptr, nullptr, nullptr, nullptr,
        Bc * Pc, HIDc, HIDc);
}